// Round 9
// baseline (123.589 us; speedup 1.0000x reference)
//
#include <hip/hip_runtime.h>
#include <math.h>

// Problem constants
#define BATCH 32
#define H 512
#define W 512
#define OUT_HW 502          // 512 - 11 + 1
#define TS_X 32             // output strip width
#define BAND 32             // output rows per band
#define NBANDS 4
#define STRIP (BAND * NBANDS)   // 128 output rows per block
#define RB_ROWS 42          // band window: 32 outputs + 10 halo
#define RB_STRIDE 36        // LDS row stride (floats): 32 data + 4 pad (bank spread)
#define NTX 16              // 512/32 column strips
#define NSTRIP 4            // 4 row strips of 128
#define NBLOCKS (NTX * NSTRIP * BATCH)   // 2048
#define N1 ((double)BATCH * H * W)            // MSE denom
#define N2 ((double)BATCH * OUT_HW * OUT_HW)  // SSIM denom

struct GaussW { float g[11]; };

// Launch-bounds history (do not re-break this):
//   (256,3) R1: VGPR capped 170 -> spill disaster; (256,4) R3: 64-VGPR dive, 2 GB scratch
//   (256,2) R2..R8: sane. R8: VGPR 56, WRITE_SIZE 32 B.
// R9: R8 structure, NSTRIP 2->4 (grid 1024->2048 blocks). R8 was occupancy-
// starved: 4 blocks/CU exactly, VALUBusy 52%, ~23 us of stall. 24.6 KB LDS
// allows 6 blocks/CU resident; 2048 blocks gives the scheduler headroom.
// Cost: stage-A halo amortization 266/256 -> 138/128 rows (+3.7% VALU).
__global__ __launch_bounds__(256, 2)
void ssim_strip_kernel(const float* __restrict__ pred,
                       const float* __restrict__ targ,
                       float* __restrict__ ws_contrib,
                       GaussW gw)
{
    __shared__ __align__(16) float rb[4][RB_ROWS * RB_STRIDE];
    __shared__ float red[8];

    const int tid = threadIdx.x;
    const int tx = blockIdx.x, sy = blockIdx.y, b = blockIdx.z;
    const int ox0 = tx * TS_X;
    const int S = sy * STRIP;                    // first output/input row of strip
    const int cols = min(TS_X, OUT_HW - ox0);    // valid output cols (32, or 22 for tx=15)
    const int mse_end = S + STRIP;               // strip owns input rows [S, S+128)
    const bool interior_x = (ox0 + 44 <= W);     // all 16-px windows in-bounds (tx<=14)

    const float* __restrict__ pb = pred + (size_t)b * H * W;
    const float* __restrict__ tb = targ + (size_t)b * H * W;

    // Stage-B per-thread constants (2 rows x 2 cols per thread, 256 items/band)
    const int br0 = 2 * (tid >> 4);
    const int bc0 = 2 * (tid & 15);

    float mse_local = 0.f, ssim_local = 0.f;

    #pragma unroll 1
    for (int band = 0; band < NBANDS; ++band) {
        const int out0  = S + band * BAND;             // first output row of band
        const int brows = min(BAND, OUT_HW - out0);    // 32, or 22 (last band, last strip)
        const int h0    = (band == 0) ? S : (out0 + 10); // first NEW h-blur row
        const int h1    = min(out0 + brows + 10, H);     // end of new h-rows
        const int nnew  = h1 - h0;                       // 42 / 32 / 22
        const int slot0 = h0 - out0;                     // LDS slot of first new row (0 or 10)

        if (band > 0) {
            __syncthreads();            // previous stage B done reading
            // copy-down: slots 32..41 (rows out0..out0+9) -> slots 0..9
            if (tid < 80) {
                const int r = tid >> 3, q = (tid & 7) * 4;
                const int src = (32 + r) * RB_STRIDE + q;
                const int dst = r * RB_STRIDE + q;
                float4 v0 = *(const float4*)&rb[0][src];
                float4 v1 = *(const float4*)&rb[1][src];
                float4 v2 = *(const float4*)&rb[2][src];
                float4 v3 = *(const float4*)&rb[3][src];
                *(float4*)&rb[0][dst] = v0;
                *(float4*)&rb[1][dst] = v1;
                *(float4*)&rb[2][dst] = v2;
                *(float4*)&rb[3][dst] = v3;
            }
            __syncthreads();            // copy visible before stage A overwrites 10..41
        }

        // ---- Stage A: h-blur the nnew new rows into slots slot0..slot0+nnew-1
        #pragma unroll 1
        for (int idx = tid; idx < nnew * 8; idx += 256) {
            const int r = idx >> 3, gq = idx & 7;
            const int c0 = 4 * gq;
            const int gy = h0 + r;                      // < H by construction
            const float* prow = pb + ((size_t)gy << 9) + ox0 + c0;
            const float* trow = tb + ((size_t)gy << 9) + ox0 + c0;
            float sv[16], dv[16], ss[16], dd[16];
            if (interior_x) {           // block-uniform branch: no divergence
                #pragma unroll
                for (int q = 0; q < 4; ++q) {
                    *(float4*)(sv + 4 * q) = *(const float4*)(prow + 4 * q);
                    *(float4*)(dv + 4 * q) = *(const float4*)(trow + 4 * q);
                }
            } else {
                #pragma unroll
                for (int q = 0; q < 4; ++q) {
                    int gx = ox0 + c0 + 4 * q;
                    float4 vp = make_float4(0.f, 0.f, 0.f, 0.f);
                    float4 vt = vp;
                    if (gx < W) {       // 16B-aligned: all-or-nothing
                        vp = *(const float4*)(prow + 4 * q);
                        vt = *(const float4*)(trow + 4 * q);
                    }
                    *(float4*)(sv + 4 * q) = vp;
                    *(float4*)(dv + 4 * q) = vt;
                }
            }
            #pragma unroll
            for (int i = 0; i < 16; ++i) {
                float p = sv[i], t = dv[i];
                float s = p + t, d = p - t;
                sv[i] = s; dv[i] = d;
                ss[i] = s * s; dd[i] = d * d;
            }

            // MSE: strip owns input rows [S, S+128); each h-row processed once.
            // First f4 (cols ox0+c0..+3) = exact x-cover across the 8 groups.
            if (gy < mse_end)
                mse_local += dd[0] + dd[1] + dd[2] + dd[3];

            float a[4][4] = {};
            #pragma unroll
            for (int k = 0; k < 11; ++k) {
                float g = gw.g[k];
                #pragma unroll
                for (int j = 0; j < 4; ++j) {
                    a[0][j] = fmaf(g, sv[j + k], a[0][j]);
                    a[1][j] = fmaf(g, dv[j + k], a[1][j]);
                    a[2][j] = fmaf(g, ss[j + k], a[2][j]);
                    a[3][j] = fmaf(g, dd[j + k], a[3][j]);
                }
            }
            const int wr = (slot0 + r) * RB_STRIDE + c0;
            #pragma unroll
            for (int ch = 0; ch < 4; ++ch)
                *(float4*)(&rb[ch][wr]) = make_float4(a[ch][0], a[ch][1], a[ch][2], a[ch][3]);
        }
        __syncthreads();

        // ---- Stage B: vertical blur, 2 rows x 2 cols per thread (slots 0..41)
        if (br0 < brows) {
            float acc[4][2][2] = {};   // [ch][row i][col j]
            #pragma unroll
            for (int jr = 0; jr < 12; ++jr) {
                int rr = br0 + jr;
                #pragma unroll
                for (int ch = 0; ch < 4; ++ch) {
                    float2 v = *(const float2*)(&rb[ch][rr * RB_STRIDE + bc0]);
                    #pragma unroll
                    for (int i = 0; i < 2; ++i) {
                        int k = jr - i;
                        if (k >= 0 && k < 11) {
                            float g = gw.g[k];
                            acc[ch][i][0] = fmaf(g, v.x, acc[ch][i][0]);
                            acc[ch][i][1] = fmaf(g, v.y, acc[ch][i][1]);
                        }
                    }
                }
            }
            const float C1 = 1e-4f, C2 = 9e-4f;
            #pragma unroll
            for (int i = 0; i < 2; ++i) {
                if (br0 + i < brows) {
                    #pragma unroll
                    for (int j = 0; j < 2; ++j) {
                        if (bc0 + j < cols) {
                            float A  = acc[0][i][j], Bv = acc[1][i][j];
                            float U  = acc[2][i][j], V  = acc[3][i][j];
                            float A2 = A * A, B2 = Bv * Bv;
                            float mu12_2 = 0.5f * (A2 - B2);      // 2*mu1*mu2
                            float musq   = 0.5f * (A2 + B2);      // mu1^2+mu2^2
                            float sig12_2 = 0.5f * (U - V) - mu12_2;
                            float sigsum  = 0.5f * (U + V) - musq;
                            float num = (mu12_2 + C1) * (sig12_2 + C2);
                            float den = (musq + C1) * (sigsum + C2) + 1e-6f;
                            ssim_local += num / den;
                        }
                    }
                }
            }
        }
        // WAR hazard vs next band's copy/A handled by loop-top barrier
    }

    // ---- Block reduction (once per block; 256 threads = 4 waves)
    #pragma unroll
    for (int off = 32; off > 0; off >>= 1) {
        ssim_local += __shfl_down(ssim_local, off, 64);
        mse_local  += __shfl_down(mse_local,  off, 64);
    }
    int wave = tid >> 6;
    if ((tid & 63) == 0) { red[wave] = ssim_local; red[4 + wave] = mse_local; }
    __syncthreads();
    if (tid == 0) {
        float s = red[0] + red[1] + red[2] + red[3];
        float m = red[4] + red[5] + red[6] + red[7];
        double contrib = 0.6 * (double)m / N1 - 0.4 * (double)s / N2;
        int bid = (b * NSTRIP + sy) * NTX + tx;
        ws_contrib[bid] = (float)contrib;
    }
}

__global__ __launch_bounds__(1024)
void finalize_kernel(const float* __restrict__ ws_contrib,
                     float* __restrict__ out)
{
    __shared__ double rs[1024];
    int tid = threadIdx.x;
    double s = 0.0;
    for (int i = tid; i < NBLOCKS; i += 1024)
        s += (double)ws_contrib[i];
    rs[tid] = s;
    __syncthreads();
    for (int off = 512; off > 0; off >>= 1) {
        if (tid < off) rs[tid] += rs[tid + off];
        __syncthreads();
    }
    if (tid == 0)
        out[0] = (float)(0.4 + rs[0]);
}

extern "C" void kernel_launch(void* const* d_in, const int* in_sizes, int n_in,
                              void* d_out, int out_size, void* d_ws, size_t ws_size,
                              hipStream_t stream)
{
    const float* pred = (const float*)d_in[0];
    const float* targ = (const float*)d_in[1];
    float* out = (float*)d_out;
    float* ws_contrib = (float*)d_ws;

    // Gaussian taps: computed host-side in double, normalized, passed by value.
    GaussW gw;
    double g[11], sum = 0.0;
    for (int i = 0; i < 11; ++i) { double x = i - 5.0; g[i] = exp(-x * x / 4.5); sum += g[i]; }
    for (int i = 0; i < 11; ++i) gw.g[i] = (float)(g[i] / sum);

    ssim_strip_kernel<<<dim3(NTX, NSTRIP, BATCH), 256, 0, stream>>>(pred, targ, ws_contrib, gw);
    finalize_kernel<<<1, 1024, 0, stream>>>(ws_contrib, out);
}

// Round 10
// 123.226 us; speedup vs baseline: 1.0030x; 1.0030x over previous
//
#include <hip/hip_runtime.h>
#include <math.h>

// Problem constants
#define BATCH 32
#define H 512
#define W 512
#define OUT_HW 502          // 512 - 11 + 1
#define TS_X 32             // output strip width
#define BAND 64             // output rows per band (R10: was 32)
#define NBANDS 2
#define STRIP (BAND * NBANDS)   // 128 output rows per block
#define RB_ROWS 74          // band window: 64 outputs + 10 halo
#define RB_STRIDE 36        // LDS row stride (floats): 32 data + 4 pad
#define NTX 16              // 512/32 column strips
#define NSTRIP 4            // 4 row strips of 128
#define NBLOCKS (NTX * NSTRIP * BATCH)   // 2048
#define N1 ((double)BATCH * H * W)            // MSE denom
#define N2 ((double)BATCH * OUT_HW * OUT_HW)  // SSIM denom

struct GaussW { float g[11]; };

// Launch-bounds history (do not re-break this):
//   (256,3) R1: VGPR capped 170 -> spill disaster; (256,4) R3: 64-VGPR dive, 2 GB scratch
//   (256,2) R2..R9: sane. R9: VGPR 56, WRITE 64 B.
// R10: R9 was co-limited by VALU (~27us) and DS (~27us est) with ~12 barriers.
// BAND 32->64: stage B goes 2rows/thread -> 4rows/thread (ds_read_b64 per
// output 12 -> 7, -42% DS instrs), barriers per block 12 -> 6, copy-down
// amortized 2x. LDS 24.6 -> 42.6 KB (3 blocks/CU resident; R9 proved we are
// not TLP-starved). Stage A unchanged ((s,d) transform, 1.08x halo).
__global__ __launch_bounds__(256, 2)
void ssim_strip_kernel(const float* __restrict__ pred,
                       const float* __restrict__ targ,
                       float* __restrict__ ws_contrib,
                       GaussW gw)
{
    __shared__ __align__(16) float rb[4][RB_ROWS * RB_STRIDE];
    __shared__ float red[8];

    const int tid = threadIdx.x;
    const int tx = blockIdx.x, sy = blockIdx.y, b = blockIdx.z;
    const int ox0 = tx * TS_X;
    const int S = sy * STRIP;                    // first output/input row of strip
    const int cols = min(TS_X, OUT_HW - ox0);    // valid output cols (32, or 22 for tx=15)
    const int mse_end = S + STRIP;               // strip owns input rows [S, S+128)
    const bool interior_x = (ox0 + 44 <= W);     // all 16-px windows in-bounds (tx<=14)

    // 32-bit offsets from SGPR image base (saddr addressing; avoids 64-bit VALU adds)
    const float* __restrict__ pb = pred + ((size_t)b << 18);
    const float* __restrict__ tb = targ + ((size_t)b << 18);

    // Stage-B per-thread constants (4 rows x 2 cols per thread, 256 items/band)
    const int br0 = 4 * (tid >> 4);
    const int bc0 = 2 * (tid & 15);

    float mse_local = 0.f, ssim_local = 0.f;

    #pragma unroll 1
    for (int band = 0; band < NBANDS; ++band) {
        const int out0  = S + band * BAND;             // first output row of band
        const int brows = min(BAND, OUT_HW - out0);    // 64, or 54 (last band, last strip)
        const int h0    = (band == 0) ? S : (out0 + 10); // first NEW h-blur row
        const int h1    = min(out0 + brows + 10, H);     // end of new h-rows
        const int nnew  = h1 - h0;                       // 74 / 64 / 54
        const int slot0 = h0 - out0;                     // LDS slot of first new row (0 or 10)

        if (band > 0) {
            __syncthreads();            // previous stage B done reading
            // copy-down: slots 64..73 (rows out0..out0+9) -> slots 0..9
            if (tid < 80) {
                const int r = tid >> 3, q = (tid & 7) * 4;
                const int src = (BAND + r) * RB_STRIDE + q;
                const int dst = r * RB_STRIDE + q;
                float4 v0 = *(const float4*)&rb[0][src];
                float4 v1 = *(const float4*)&rb[1][src];
                float4 v2 = *(const float4*)&rb[2][src];
                float4 v3 = *(const float4*)&rb[3][src];
                *(float4*)&rb[0][dst] = v0;
                *(float4*)&rb[1][dst] = v1;
                *(float4*)&rb[2][dst] = v2;
                *(float4*)&rb[3][dst] = v3;
            }
            __syncthreads();            // copy visible before stage A overwrites 10..73
        }

        // ---- Stage A: h-blur the nnew new rows into slots slot0..slot0+nnew-1
        #pragma unroll 1
        for (int idx = tid; idx < nnew * 8; idx += 256) {
            const int r = idx >> 3, gq = idx & 7;
            const int c0 = 4 * gq;
            const int gy = h0 + r;                      // < H by construction
            const int base = (gy << 9) + ox0 + c0;      // 32-bit element offset
            float sv[16], dv[16], ss[16], dd[16];
            if (interior_x) {           // block-uniform branch: no divergence
                #pragma unroll
                for (int q = 0; q < 4; ++q) {
                    *(float4*)(sv + 4 * q) = *(const float4*)(pb + base + 4 * q);
                    *(float4*)(dv + 4 * q) = *(const float4*)(tb + base + 4 * q);
                }
            } else {
                #pragma unroll
                for (int q = 0; q < 4; ++q) {
                    int gx = ox0 + c0 + 4 * q;
                    float4 vp = make_float4(0.f, 0.f, 0.f, 0.f);
                    float4 vt = vp;
                    if (gx < W) {       // 16B-aligned: all-or-nothing
                        vp = *(const float4*)(pb + base + 4 * q);
                        vt = *(const float4*)(tb + base + 4 * q);
                    }
                    *(float4*)(sv + 4 * q) = vp;
                    *(float4*)(dv + 4 * q) = vt;
                }
            }
            #pragma unroll
            for (int i = 0; i < 16; ++i) {
                float p = sv[i], t = dv[i];
                float s = p + t, d = p - t;
                sv[i] = s; dv[i] = d;
                ss[i] = s * s; dd[i] = d * d;
            }

            // MSE: strip owns input rows [S, S+128); each h-row processed once.
            // First f4 (cols ox0+c0..+3) = exact x-cover across the 8 groups.
            if (gy < mse_end)
                mse_local += dd[0] + dd[1] + dd[2] + dd[3];

            float a[4][4] = {};
            #pragma unroll
            for (int k = 0; k < 11; ++k) {
                float g = gw.g[k];
                #pragma unroll
                for (int j = 0; j < 4; ++j) {
                    a[0][j] = fmaf(g, sv[j + k], a[0][j]);
                    a[1][j] = fmaf(g, dv[j + k], a[1][j]);
                    a[2][j] = fmaf(g, ss[j + k], a[2][j]);
                    a[3][j] = fmaf(g, dd[j + k], a[3][j]);
                }
            }
            const int wr = (slot0 + r) * RB_STRIDE + c0;
            #pragma unroll
            for (int ch = 0; ch < 4; ++ch)
                *(float4*)(&rb[ch][wr]) = make_float4(a[ch][0], a[ch][1], a[ch][2], a[ch][3]);
        }
        __syncthreads();

        // ---- Stage B: vertical blur, 4 rows x 2 cols per thread (slots 0..73)
        if (br0 < brows) {
            float acc[4][4][2] = {};   // [ch][row i][col j]
            #pragma unroll
            for (int jr = 0; jr < 14; ++jr) {
                int rr = br0 + jr;
                #pragma unroll
                for (int ch = 0; ch < 4; ++ch) {
                    float2 v = *(const float2*)(&rb[ch][rr * RB_STRIDE + bc0]);
                    #pragma unroll
                    for (int i = 0; i < 4; ++i) {
                        int k = jr - i;
                        if (k >= 0 && k < 11) {
                            float g = gw.g[k];
                            acc[ch][i][0] = fmaf(g, v.x, acc[ch][i][0]);
                            acc[ch][i][1] = fmaf(g, v.y, acc[ch][i][1]);
                        }
                    }
                }
            }
            const float C1 = 1e-4f, C2 = 9e-4f;
            #pragma unroll
            for (int i = 0; i < 4; ++i) {
                if (br0 + i < brows) {
                    #pragma unroll
                    for (int j = 0; j < 2; ++j) {
                        if (bc0 + j < cols) {
                            float A  = acc[0][i][j], Bv = acc[1][i][j];
                            float U  = acc[2][i][j], V  = acc[3][i][j];
                            float A2 = A * A, B2 = Bv * Bv;
                            float mu12_2 = 0.5f * (A2 - B2);      // 2*mu1*mu2
                            float musq   = 0.5f * (A2 + B2);      // mu1^2+mu2^2
                            float sig12_2 = 0.5f * (U - V) - mu12_2;
                            float sigsum  = 0.5f * (U + V) - musq;
                            float num = (mu12_2 + C1) * (sig12_2 + C2);
                            float den = (musq + C1) * (sigsum + C2) + 1e-6f;
                            ssim_local += num / den;
                        }
                    }
                }
            }
        }
        // WAR hazard vs next band's copy/A handled by loop-top barrier
    }

    // ---- Block reduction (once per block; 256 threads = 4 waves)
    #pragma unroll
    for (int off = 32; off > 0; off >>= 1) {
        ssim_local += __shfl_down(ssim_local, off, 64);
        mse_local  += __shfl_down(mse_local,  off, 64);
    }
    int wave = tid >> 6;
    if ((tid & 63) == 0) { red[wave] = ssim_local; red[4 + wave] = mse_local; }
    __syncthreads();
    if (tid == 0) {
        float s = red[0] + red[1] + red[2] + red[3];
        float m = red[4] + red[5] + red[6] + red[7];
        double contrib = 0.6 * (double)m / N1 - 0.4 * (double)s / N2;
        int bid = (b * NSTRIP + sy) * NTX + tx;
        ws_contrib[bid] = (float)contrib;
    }
}

__global__ __launch_bounds__(1024)
void finalize_kernel(const float* __restrict__ ws_contrib,
                     float* __restrict__ out)
{
    __shared__ double rs[1024];
    int tid = threadIdx.x;
    double s = 0.0;
    for (int i = tid; i < NBLOCKS; i += 1024)
        s += (double)ws_contrib[i];
    rs[tid] = s;
    __syncthreads();
    for (int off = 512; off > 0; off >>= 1) {
        if (tid < off) rs[tid] += rs[tid + off];
        __syncthreads();
    }
    if (tid == 0)
        out[0] = (float)(0.4 + rs[0]);
}

extern "C" void kernel_launch(void* const* d_in, const int* in_sizes, int n_in,
                              void* d_out, int out_size, void* d_ws, size_t ws_size,
                              hipStream_t stream)
{
    const float* pred = (const float*)d_in[0];
    const float* targ = (const float*)d_in[1];
    float* out = (float*)d_out;
    float* ws_contrib = (float*)d_ws;

    // Gaussian taps: computed host-side in double, normalized, passed by value.
    GaussW gw;
    double g[11], sum = 0.0;
    for (int i = 0; i < 11; ++i) { double x = i - 5.0; g[i] = exp(-x * x / 4.5); sum += g[i]; }
    for (int i = 0; i < 11; ++i) gw.g[i] = (float)(g[i] / sum);

    ssim_strip_kernel<<<dim3(NTX, NSTRIP, BATCH), 256, 0, stream>>>(pred, targ, ws_contrib, gw);
    finalize_kernel<<<1, 1024, 0, stream>>>(ws_contrib, out);
}